// Round 1
// baseline (686.069 us; speedup 1.0000x reference)
//
#include <hip/hip_runtime.h>

// Problem constants
#define BB   4
#define CC   128
#define DHW  32768           // 32*32*32
#define NN   131072          // BB*DHW
#define KK   1024

// Output layout (floats, concatenated in reference return order)
#define OUT_Q    0
#define OUT_LOSS 16777216
#define OUT_IDX  16777217
#define OUT_ESUM 16908289
#define OUT_EMB  16908545
// total out_size = 17039617

// Workspace layout (float offsets). Needs ~1.05 MB of ws.
#define WS_EMBT  0           // 131072 floats: embT[c][k]
#define WS_ENH   131072      // 1024 floats: 0.5*||e_k||^2
#define WS_LOSS  132096      // 1 float accumulator
#define WS_IDX   132100      // 131072 ints (16B aligned: 132100*4 % 16 == 0)

// ---------------------------------------------------------------------------
// prep: transpose embedding -> embT[C][K], compute 0.5*||e||^2, zero loss acc
// ---------------------------------------------------------------------------
__global__ __launch_bounds__(128) void prep_kernel(const float* __restrict__ emb,
                                                   float* __restrict__ embT,
                                                   float* __restrict__ enh,
                                                   float* __restrict__ loss_acc) {
    const int k = blockIdx.x;     // 0..1023
    const int c = threadIdx.x;    // 0..127
    float v = emb[k * CC + c];    // coalesced read
    embT[c * KK + k] = v;         // strided write; 512 KB total, L2 absorbs
    float s = v * v;
    #pragma unroll
    for (int o = 32; o > 0; o >>= 1) s += __shfl_down(s, o);
    __shared__ float part[2];
    if ((c & 63) == 0) part[c >> 6] = s;
    __syncthreads();
    if (c == 0) {
        enh[k] = 0.5f * (part[0] + part[1]);
        if (k == 0) *loss_acc = 0.0f;
    }
}

// ---------------------------------------------------------------------------
// argmin: for each of 64 vectors/block, find nearest code among 1024.
// key = 0.5*||e||^2 - x.e  (same ordering as full squared distance)
// Tile: 64 vec x 64 codes per chunk; each thread: 4 vec x 4 codes outer product.
// LDS: x4[128][16] float4, e4[128][16] float4 (64 KB total).
// Inner-loop reads: x b128 -> 16 addrs over 64 words = 2/bank (free);
//                   e b128 -> 4 addrs x16 broadcast (free).
// ---------------------------------------------------------------------------
__global__ __launch_bounds__(256) void argmin_kernel(const float* __restrict__ x,
                                                     const float* __restrict__ embT,
                                                     const float* __restrict__ enh,
                                                     int* __restrict__ out_idx) {
    extern __shared__ float4 smem[];
    float4* x4 = smem;             // [128][16]
    float4* e4 = smem + 128 * 16;  // [128][16]

    const int t  = threadIdx.x;
    const int tv = t & 15;         // vector group (4 vecs each)
    const int tc = t >> 4;         // code group (4 codes each)
    const int n0 = blockIdx.x * 64;
    const int b  = n0 >> 15;
    const int dhw0 = n0 & (DHW - 1);
    const float* xb = x + (size_t)b * CC * DHW + dhw0;

    // stage x tile: 64 vectors x 128 channels, transposed to [c][vec]
    {
        const int cc0 = t >> 4, q = t & 15;
        #pragma unroll
        for (int p = 0; p < 8; ++p) {
            const int c = p * 16 + cc0;
            x4[c * 16 + q] = *(const float4*)(xb + (size_t)c * DHW + 4 * q);
        }
    }

    float best_val[4] = {1e30f, 1e30f, 1e30f, 1e30f};
    int   best_idx[4] = {0, 0, 0, 0};

    for (int k0 = 0; k0 < KK; k0 += 64) {
        __syncthreads();  // protects x staging (first iter) / prev e4 reads
        {   // stage e tile: 64 codes x 128 channels, [c][code] from embT
            const int cc0 = t >> 4, q = t & 15;
            #pragma unroll
            for (int p = 0; p < 8; ++p) {
                const int c = p * 16 + cc0;
                e4[c * 16 + q] = *(const float4*)(embT + c * KK + k0 + 4 * q);
            }
        }
        __syncthreads();

        float acc[4][4];
        #pragma unroll
        for (int i = 0; i < 4; ++i)
            #pragma unroll
            for (int j = 0; j < 4; ++j) acc[i][j] = 0.0f;

        #pragma unroll 4
        for (int c = 0; c < CC; ++c) {
            const float4 xv = x4[c * 16 + tv];
            const float4 ev = e4[c * 16 + tc];
            const float xs[4] = {xv.x, xv.y, xv.z, xv.w};
            const float es[4] = {ev.x, ev.y, ev.z, ev.w};
            #pragma unroll
            for (int i = 0; i < 4; ++i)
                #pragma unroll
                for (int j = 0; j < 4; ++j)
                    acc[i][j] = fmaf(xs[i], es[j], acc[i][j]);
        }

        const float4 en = *(const float4*)(enh + k0 + tc * 4);
        const float ens[4] = {en.x, en.y, en.z, en.w};
        #pragma unroll
        for (int i = 0; i < 4; ++i) {
            #pragma unroll
            for (int j = 0; j < 4; ++j) {
                const float key = ens[j] - acc[i][j];
                if (key < best_val[i]) {           // strict < keeps earliest k
                    best_val[i] = key;
                    best_idx[i] = k0 + tc * 4 + j;
                }
            }
        }
    }

    // cross-thread reduction over the 16 code-groups per vector
    __syncthreads();
    float* rv = (float*)e4;
    int*   ri = (int*)x4;
    #pragma unroll
    for (int i = 0; i < 4; ++i) {
        const int v = tv * 4 + i;
        rv[v * 16 + tc] = best_val[i];
        ri[v * 16 + tc] = best_idx[i];
    }
    __syncthreads();
    if (t < 64) {
        float bv = 1e30f; int bi = 1 << 30;
        #pragma unroll
        for (int q = 0; q < 16; ++q) {
            const float v = rv[t * 16 + q];
            const int  id = ri[t * 16 + q];
            if (v < bv || (v == bv && id < bi)) { bv = v; bi = id; }
        }
        out_idx[n0 + t] = bi;
    }
}

// ---------------------------------------------------------------------------
// quant: gather codes, write straight-through output, accumulate loss sum.
// out = in + (q - in), loss += (q - in)^2. Gather via embT rows (L1-hot 4KB).
// ---------------------------------------------------------------------------
__global__ __launch_bounds__(256) void quant_kernel(const float* __restrict__ x,
                                                    const float* __restrict__ embT,
                                                    const int* __restrict__ idx,
                                                    float* __restrict__ out,
                                                    float* __restrict__ loss_acc) {
    const int bid   = blockIdx.x;           // 0..511
    const int c0    = (bid & 3) * 32;
    const int chunk = bid >> 2;             // 0..127
    const int b     = chunk >> 5;           // 0..3
    const int dhw   = (chunk & 31) * 1024 + threadIdx.x * 4;
    const int n     = b * DHW + dhw;
    const int4 kk   = *(const int4*)(idx + n);
    const size_t base = (size_t)b * CC * DHW + dhw;

    float lacc = 0.0f;
    for (int c = c0; c < c0 + 32; ++c) {
        const float4 in4 = *(const float4*)(x + base + (size_t)c * DHW);
        const float* er  = embT + c * KK;
        const float d0 = er[kk.x] - in4.x;
        const float d1 = er[kk.y] - in4.y;
        const float d2 = er[kk.z] - in4.z;
        const float d3 = er[kk.w] - in4.w;
        float4 o4;
        o4.x = in4.x + d0; o4.y = in4.y + d1;
        o4.z = in4.z + d2; o4.w = in4.w + d3;
        *(float4*)(out + base + (size_t)c * DHW) = o4;
        lacc += d0 * d0 + d1 * d1 + d2 * d2 + d3 * d3;
    }
    #pragma unroll
    for (int o = 32; o > 0; o >>= 1) lacc += __shfl_down(lacc, o);
    __shared__ float part[4];
    if ((threadIdx.x & 63) == 0) part[threadIdx.x >> 6] = lacc;
    __syncthreads();
    if (threadIdx.x == 0)
        atomicAdd(loss_acc, part[0] + part[1] + part[2] + part[3]);
}

// ---------------------------------------------------------------------------
// tail: indices as float, embedding copy, encodings_sum zeros, loss finalize
// ---------------------------------------------------------------------------
__global__ __launch_bounds__(256) void tail_kernel(const int* __restrict__ idx,
                                                   const float* __restrict__ emb,
                                                   const float* __restrict__ loss_acc,
                                                   float* __restrict__ out) {
    const int g = blockIdx.x * 256 + threadIdx.x;
    if (g < NN) {
        out[OUT_IDX + g] = (float)idx[g];
    } else if (g < 2 * NN) {
        out[OUT_EMB + (g - NN)] = emb[g - NN];
    } else if (g < 2 * NN + 256) {
        out[OUT_ESUM + (g - 2 * NN)] = 0.0f;
    } else if (g == 2 * NN + 256) {
        // loss = 0.25 * mean((q - x)^2) * 10 = 2.5 * sum / numel
        out[OUT_LOSS] = 2.5f * (*loss_acc) / 16777216.0f;
    }
}

extern "C" void kernel_launch(void* const* d_in, const int* in_sizes, int n_in,
                              void* d_out, int out_size, void* d_ws, size_t ws_size,
                              hipStream_t stream) {
    const float* x   = (const float*)d_in[0];   // [4,128,32,32,32] fp32
    const float* emb = (const float*)d_in[1];   // [1024,128] fp32
    float* out = (float*)d_out;
    float* ws  = (float*)d_ws;

    float* embT     = ws + WS_EMBT;
    float* enh      = ws + WS_ENH;
    float* loss_acc = ws + WS_LOSS;
    int*   idx      = (int*)(ws + WS_IDX);

    prep_kernel<<<KK, 128, 0, stream>>>(emb, embT, enh, loss_acc);
    argmin_kernel<<<NN / 64, 256, 2 * 128 * 16 * sizeof(float4), stream>>>(x, embT, enh, idx);
    quant_kernel<<<512, 256, 0, stream>>>(x, embT, idx, out, loss_acc);
    tail_kernel<<<(2 * NN + 256 + 256) / 256 + 1, 256, 0, stream>>>(idx, emb, loss_acc, out);
}